// Round 2
// baseline (1207.724 us; speedup 1.0000x reference)
//
#include <hip/hip_runtime.h>
#include <math.h>

#define R 1024
#define CIN 256
#define CHID 32
#define NH 8
#define CZ 128
#define EPS 1e-5f

// ---------------- K1: mn = LayerNorm(m) ----------------
__global__ __launch_bounds__(256) void k_ln_m(const float* __restrict__ m,
        const float* __restrict__ w, const float* __restrict__ b,
        float* __restrict__ mn) {
    int row = blockIdx.x;
    int tid = threadIdx.x;
    float x = m[row * CIN + tid];
    float s1 = x, s2 = x * x;
    #pragma unroll
    for (int mm = 1; mm < 64; mm <<= 1) {
        s1 += __shfl_xor(s1, mm);
        s2 += __shfl_xor(s2, mm);
    }
    __shared__ float red[8];
    int wave = tid >> 6;
    if ((tid & 63) == 0) { red[wave * 2] = s1; red[wave * 2 + 1] = s2; }
    __syncthreads();
    float t1 = red[0] + red[2] + red[4] + red[6];
    float t2 = red[1] + red[3] + red[5] + red[7];
    float mu = t1 * (1.0f / CIN);
    float var = t2 * (1.0f / CIN) - mu * mu;
    float rstd = rsqrtf(var + EPS);
    mn[row * CIN + tid] = (x - mu) * rstd * w[tid] + b[tid];
}

// ---------------- K2: QS/KS/VT/GS = mn @ {Wq,Wk,Wv,Wg} ----------------
// grid = 4 mats * 256 tiles of 4 rows. Batched W loads (8 in flight, ping-pong).
// V is stored TRANSPOSED: VT[col][k] so k_attn phase 3 can stream float4.
__global__ __launch_bounds__(256) void k_qkvg(const float* __restrict__ mn,
        const float* __restrict__ Wq, const float* __restrict__ Wk,
        const float* __restrict__ Wv, const float* __restrict__ Wg,
        float* __restrict__ QS, float* __restrict__ KS,
        float* __restrict__ VT, float* __restrict__ GS) {
    __shared__ __align__(16) float mnt[CIN * 4];   // mnt[c][r], float4 per c
    int tid = threadIdx.x;
    int mat = blockIdx.x >> 8;
    int qb = (blockIdx.x & 255) * 4;
    #pragma unroll
    for (int r = 0; r < 4; ++r)
        mnt[tid * 4 + r] = mn[(qb + r) * CIN + tid];
    __syncthreads();
    const float* W = (mat == 0) ? Wq : (mat == 1) ? Wk : (mat == 2) ? Wv : Wg;
    const float4* mt4 = (const float4*)mnt;
    float acc[4] = {0.f, 0.f, 0.f, 0.f};
    float wa[8], wb[8];
    #pragma unroll
    for (int u = 0; u < 8; ++u) wa[u] = W[u * 256 + tid];
    for (int g = 0; g < 32; g += 2) {
        #pragma unroll
        for (int u = 0; u < 8; ++u) wb[u] = W[((g + 1) * 8 + u) * 256 + tid];
        #pragma unroll
        for (int u = 0; u < 8; ++u) {
            float4 mv = mt4[g * 8 + u];
            float wv = wa[u];
            acc[0] += mv.x * wv; acc[1] += mv.y * wv;
            acc[2] += mv.z * wv; acc[3] += mv.w * wv;
        }
        #pragma unroll
        for (int u = 0; u < 8; ++u) {
            int cb = (g + 2 < 32) ? ((g + 2) * 8 + u) : u;
            wa[u] = W[cb * 256 + tid];
        }
        #pragma unroll
        for (int u = 0; u < 8; ++u) {
            float4 mv = mt4[(g + 1) * 8 + u];
            float wv = wb[u];
            acc[0] += mv.x * wv; acc[1] += mv.y * wv;
            acc[2] += mv.z * wv; acc[3] += mv.w * wv;
        }
    }
    if (mat == 2) {
        // transposed store: VT[tid][qb..qb+3], contiguous float4
        *(float4*)(VT + (size_t)tid * R + qb) =
            make_float4(acc[0], acc[1], acc[2], acc[3]);
    } else {
        float* OUT = (mat == 0) ? QS : (mat == 1) ? KS : GS;
        #pragma unroll
        for (int r = 0; r < 4; ++r) {
            float v = acc[r];
            if (mat == 0) v *= 0.17677669529663687f;      // 1/sqrt(32)
            if (mat == 3) v = 1.f / (1.f + __expf(-v));   // sigmoid
            OUT[(qb + r) * 256 + tid] = v;
        }
    }
}

// ---------------- K3: fused pair-bias(z) + attention + gate ----------------
// One block per query row. Deep-MLP register double-buffering on all streams.
__global__ __launch_bounds__(256, 4) void k_attn(
        const float* __restrict__ z, const float* __restrict__ lzw,
        const float* __restrict__ lzb, const float* __restrict__ Wz,
        const float* __restrict__ QS, const float* __restrict__ KS,
        const float* __restrict__ VT, const float* __restrict__ GS,
        float* __restrict__ OB) {
    __shared__ __align__(16) float s_lds[NH * R];      // 32 KB scores [h][k]
    __shared__ __align__(16) float q_lds[CIN];
    __shared__ __align__(16) float A_lds[CZ * NH];     // A[c][h] = lzw[c]*Wz[c][h]
    __shared__ float sumA[NH], constB[NH], inv_lds[NH];
    int tid = threadIdx.x;
    int q = blockIdx.x;

    if (tid < CZ) {
        float lw = lzw[tid];
        #pragma unroll
        for (int h = 0; h < NH; ++h) A_lds[tid * NH + h] = lw * Wz[tid * NH + h];
    }
    q_lds[tid] = QS[q * CIN + tid];
    __syncthreads();
    if (tid < NH) {
        float sa = 0.f, cb = 0.f;
        #pragma unroll 8
        for (int c = 0; c < CZ; ++c) {
            sa += A_lds[c * NH + tid];
            cb += lzb[c] * Wz[c * NH + tid];
        }
        sumA[tid] = sa; constB[tid] = cb;
    }
    __syncthreads();

    const float4* A4 = (const float4*)A_lds;   // A4[c*2], A4[c*2+1] = heads 0-3, 4-7
    const float4* Qr = (const float4*)q_lds;

    // ---- phase 1: scores s[h][k] = q.k + bias(z[q,k,:]) ----
    #pragma unroll 1
    for (int it = 0; it < 4; ++it) {
        int k = it * 256 + tid;
        const float4* zr = (const float4*)(z + ((size_t)q * R + (size_t)k) * CZ);
        float s1 = 0.f, s2 = 0.f;
        float d[NH];
        #pragma unroll
        for (int h = 0; h < NH; ++h) d[h] = 0.f;
        float4 za[8], zb[8];
        #pragma unroll
        for (int u = 0; u < 8; ++u) za[u] = zr[u];
        #pragma unroll
        for (int g = 0; g < 4; ++g) {
            if (g < 3) {
                #pragma unroll
                for (int u = 0; u < 8; ++u) {
                    float4 t = zr[(g + 1) * 8 + u];
                    if (g & 1) za[u] = t; else zb[u] = t;
                }
            }
            #pragma unroll
            for (int u = 0; u < 8; ++u) {
                float4 zv = (g & 1) ? zb[u] : za[u];
                int c4 = g * 8 + u;
                #pragma unroll
                for (int e = 0; e < 4; ++e) {
                    float x = (e == 0) ? zv.x : (e == 1) ? zv.y : (e == 2) ? zv.z : zv.w;
                    int c = c4 * 4 + e;
                    float4 aa = A4[c * 2];        // uniform addr -> LDS broadcast
                    float4 ab = A4[c * 2 + 1];
                    s1 += x; s2 += x * x;
                    d[0] += x * aa.x; d[1] += x * aa.y; d[2] += x * aa.z; d[3] += x * aa.w;
                    d[4] += x * ab.x; d[5] += x * ab.y; d[6] += x * ab.z; d[7] += x * ab.w;
                }
            }
        }
        float mu = s1 * (1.0f / CZ);
        float var = s2 * (1.0f / CZ) - mu * mu;
        float rstd = rsqrtf(var + EPS);

        // q.k dots, one head per 8-float4 batch, ping-pong
        const float4* Kr = (const float4*)(KS + (size_t)k * CIN);
        #pragma unroll
        for (int u = 0; u < 8; ++u) za[u] = Kr[u];
        #pragma unroll
        for (int h = 0; h < NH; ++h) {
            if (h < 7) {
                #pragma unroll
                for (int u = 0; u < 8; ++u) {
                    float4 t = Kr[(h + 1) * 8 + u];
                    if (h & 1) za[u] = t; else zb[u] = t;
                }
            }
            float qd = 0.f;
            #pragma unroll
            for (int u = 0; u < 8; ++u) {
                float4 kv = (h & 1) ? zb[u] : za[u];
                float4 qv = Qr[h * 8 + u];
                qd += kv.x * qv.x + kv.y * qv.y + kv.z * qv.z + kv.w * qv.w;
            }
            float bias = rstd * (d[h] - mu * sumA[h]) + constB[h];
            s_lds[h * R + k] = qd + bias;
        }
    }
    __syncthreads();

    // ---- phase 2: softmax per head (32 lanes per head) ----
    {
        int r = tid >> 5, j = tid & 31;
        float* srow = s_lds + r * R;
        float mx = -1e30f;
        #pragma unroll 4
        for (int i = 0; i < 32; ++i) mx = fmaxf(mx, srow[j + i * 32]);
        #pragma unroll
        for (int mm = 1; mm < 32; mm <<= 1) mx = fmaxf(mx, __shfl_xor(mx, mm));
        float sum = 0.f;
        #pragma unroll 4
        for (int i = 0; i < 32; ++i) {
            float e = __expf(srow[j + i * 32] - mx);
            srow[j + i * 32] = e;
            sum += e;
        }
        #pragma unroll
        for (int mm = 1; mm < 32; mm <<= 1) sum += __shfl_xor(sum, mm);
        if (j == 0) inv_lds[r] = 1.f / sum;
    }
    __syncthreads();

    // ---- phase 3: o[col] = (sum_k p[h,k] VT[col,k]) * inv * g ----
    {
        int h = tid >> 5;
        const float4* Vp = (const float4*)(VT + (size_t)tid * R);   // 256 float4
        const float4* P4 = (const float4*)(s_lds + h * R);          // broadcast
        float o0 = 0.f, o1 = 0.f, o2 = 0.f, o3 = 0.f;
        float4 va[8], vb[8];
        #pragma unroll
        for (int u = 0; u < 8; ++u) va[u] = Vp[u];
        for (int g = 0; g < 32; g += 2) {
            #pragma unroll
            for (int u = 0; u < 8; ++u) vb[u] = Vp[(g + 1) * 8 + u];
            #pragma unroll
            for (int u = 0; u < 8; ++u) {
                float4 p = P4[g * 8 + u];
                float4 v = va[u];
                o0 += p.x * v.x; o1 += p.y * v.y; o2 += p.z * v.z; o3 += p.w * v.w;
            }
            #pragma unroll
            for (int u = 0; u < 8; ++u) {
                int cb = (g + 2 < 32) ? ((g + 2) * 8 + u) : u;
                va[u] = Vp[cb];
            }
            #pragma unroll
            for (int u = 0; u < 8; ++u) {
                float4 p = P4[(g + 1) * 8 + u];
                float4 v = vb[u];
                o0 += p.x * v.x; o1 += p.y * v.y; o2 += p.z * v.z; o3 += p.w * v.w;
            }
        }
        float o = ((o0 + o1) + (o2 + o3)) * inv_lds[h];
        float g2 = GS[q * CIN + tid];
        OB[q * CIN + tid] = o * g2;
    }
}

// ---------------- K4: out = OB @ Wo + bo ----------------
// 256 blocks of 4 rows, same batched structure as k_qkvg.
__global__ __launch_bounds__(256) void k_out(const float* __restrict__ OB,
        const float* __restrict__ Wo, const float* __restrict__ bo,
        float* __restrict__ out) {
    __shared__ __align__(16) float mnt[CIN * 4];
    int tid = threadIdx.x;
    int qb = blockIdx.x * 4;
    #pragma unroll
    for (int r = 0; r < 4; ++r)
        mnt[tid * 4 + r] = OB[(qb + r) * CIN + tid];
    __syncthreads();
    const float4* mt4 = (const float4*)mnt;
    float acc[4] = {0.f, 0.f, 0.f, 0.f};
    float wa[8], wb[8];
    #pragma unroll
    for (int u = 0; u < 8; ++u) wa[u] = Wo[u * 256 + tid];
    for (int g = 0; g < 32; g += 2) {
        #pragma unroll
        for (int u = 0; u < 8; ++u) wb[u] = Wo[((g + 1) * 8 + u) * 256 + tid];
        #pragma unroll
        for (int u = 0; u < 8; ++u) {
            float4 mv = mt4[g * 8 + u];
            float wv = wa[u];
            acc[0] += mv.x * wv; acc[1] += mv.y * wv;
            acc[2] += mv.z * wv; acc[3] += mv.w * wv;
        }
        #pragma unroll
        for (int u = 0; u < 8; ++u) {
            int cb = (g + 2 < 32) ? ((g + 2) * 8 + u) : u;
            wa[u] = Wo[cb * 256 + tid];
        }
        #pragma unroll
        for (int u = 0; u < 8; ++u) {
            float4 mv = mt4[(g + 1) * 8 + u];
            float wv = wb[u];
            acc[0] += mv.x * wv; acc[1] += mv.y * wv;
            acc[2] += mv.z * wv; acc[3] += mv.w * wv;
        }
    }
    float bv = bo[tid];
    #pragma unroll
    for (int r = 0; r < 4; ++r)
        out[(qb + r) * 256 + tid] = acc[r] + bv;
}

extern "C" void kernel_launch(void* const* d_in, const int* in_sizes, int n_in,
                              void* d_out, int out_size, void* d_ws, size_t ws_size,
                              hipStream_t stream) {
    (void)in_sizes; (void)n_in; (void)out_size; (void)ws_size;
    const float* m   = (const float*)d_in[0];
    const float* z   = (const float*)d_in[1];
    const float* lmw = (const float*)d_in[2];
    const float* lmb = (const float*)d_in[3];
    const float* lzw = (const float*)d_in[4];
    const float* lzb = (const float*)d_in[5];
    const float* Wz  = (const float*)d_in[6];
    const float* Wq  = (const float*)d_in[7];
    const float* Wk  = (const float*)d_in[8];
    const float* Wv  = (const float*)d_in[9];
    const float* Wg  = (const float*)d_in[10];
    const float* Wo  = (const float*)d_in[12];
    const float* bo  = (const float*)d_in[13];
    float* ws = (float*)d_ws;
    float* MN = ws;                 // 1024*256
    float* QS = ws + 262144;
    float* KS = ws + 524288;
    float* VT = ws + 786432;        // transposed V: [256][1024]
    float* GS = ws + 1048576;
    float* OB = ws + 1310720;
    float* out = (float*)d_out;

    hipLaunchKernelGGL(k_ln_m, dim3(R), dim3(256), 0, stream, m, lmw, lmb, MN);
    hipLaunchKernelGGL(k_qkvg, dim3(1024), dim3(256), 0, stream,
                       MN, Wq, Wk, Wv, Wg, QS, KS, VT, GS);
    hipLaunchKernelGGL(k_attn, dim3(R), dim3(256), 0, stream,
                       z, lzw, lzb, Wz, QS, KS, VT, GS, OB);
    hipLaunchKernelGGL(k_out, dim3(256), dim3(256), 0, stream, OB, Wo, bo, out);
}

// Round 3
// 833.197 us; speedup vs baseline: 1.4495x; 1.4495x over previous
//
#include <hip/hip_runtime.h>
#include <math.h>

#define R 1024
#define CIN 256
#define NH 8
#define CZ 128
#define EPS 1e-5f
#define SROW 1025  // padded score row stride (floats): bank = (h+k)%32

// ---------------- K1: mn = LayerNorm(m) ----------------
__global__ __launch_bounds__(256) void k_ln_m(const float* __restrict__ m,
        const float* __restrict__ w, const float* __restrict__ b,
        float* __restrict__ mn) {
    int row = blockIdx.x;
    int tid = threadIdx.x;
    float x = m[row * CIN + tid];
    float s1 = x, s2 = x * x;
    #pragma unroll
    for (int mm = 1; mm < 64; mm <<= 1) {
        s1 += __shfl_xor(s1, mm);
        s2 += __shfl_xor(s2, mm);
    }
    __shared__ float red[8];
    int wave = tid >> 6;
    if ((tid & 63) == 0) { red[wave * 2] = s1; red[wave * 2 + 1] = s2; }
    __syncthreads();
    float t1 = red[0] + red[2] + red[4] + red[6];
    float t2 = red[1] + red[3] + red[5] + red[7];
    float mu = t1 * (1.0f / CIN);
    float var = t2 * (1.0f / CIN) - mu * mu;
    float rstd = rsqrtf(var + EPS);
    mn[row * CIN + tid] = (x - mu) * rstd * w[tid] + b[tid];
}

// ---------------- K2: QS/KS/VS/GS = mn @ {Wq,Wk,Wv,Wg} ----------------
__global__ __launch_bounds__(256) void k_qkvg(const float* __restrict__ mn,
        const float* __restrict__ Wq, const float* __restrict__ Wk,
        const float* __restrict__ Wv, const float* __restrict__ Wg,
        float* __restrict__ QS, float* __restrict__ KS,
        float* __restrict__ VS, float* __restrict__ GS) {
    __shared__ __align__(16) float mnt[CIN * 4];   // mnt[c][r]
    int tid = threadIdx.x;
    int mat = blockIdx.x >> 8;
    int qb = (blockIdx.x & 255) * 4;
    #pragma unroll
    for (int r = 0; r < 4; ++r)
        mnt[tid * 4 + r] = mn[(qb + r) * CIN + tid];
    __syncthreads();
    const float* W = (mat == 0) ? Wq : (mat == 1) ? Wk : (mat == 2) ? Wv : Wg;
    const float4* mt4 = (const float4*)mnt;
    float acc[4] = {0.f, 0.f, 0.f, 0.f};
    #pragma unroll 4
    for (int g = 0; g < 32; ++g) {
        float w0 = W[(g * 8 + 0) * 256 + tid];
        float w1 = W[(g * 8 + 1) * 256 + tid];
        float w2 = W[(g * 8 + 2) * 256 + tid];
        float w3 = W[(g * 8 + 3) * 256 + tid];
        float w4 = W[(g * 8 + 4) * 256 + tid];
        float w5 = W[(g * 8 + 5) * 256 + tid];
        float w6 = W[(g * 8 + 6) * 256 + tid];
        float w7 = W[(g * 8 + 7) * 256 + tid];
        #pragma unroll
        for (int u = 0; u < 8; ++u) {
            float wv = (u == 0) ? w0 : (u == 1) ? w1 : (u == 2) ? w2 : (u == 3) ? w3
                     : (u == 4) ? w4 : (u == 5) ? w5 : (u == 6) ? w6 : w7;
            float4 mv = mt4[g * 8 + u];
            acc[0] += mv.x * wv; acc[1] += mv.y * wv;
            acc[2] += mv.z * wv; acc[3] += mv.w * wv;
        }
    }
    float* OUT = (mat == 0) ? QS : (mat == 1) ? KS : (mat == 2) ? VS : GS;
    #pragma unroll
    for (int r = 0; r < 4; ++r) {
        float v = acc[r];
        if (mat == 0) v *= 0.17677669529663687f;      // 1/sqrt(32)
        if (mat == 3) v = 1.f / (1.f + __expf(-v));   // sigmoid
        OUT[(qb + r) * 256 + tid] = v;
    }
}

#define FMA4(acc, s, c) { acc.x += (s)*(c).x; acc.y += (s)*(c).y; \
                          acc.z += (s)*(c).z; acc.w += (s)*(c).w; }

// ---------------- K3: fused pair-bias(z) + attention + gate ----------------
// All global streams wave-coalesced; butterfly reductions for row stats.
__global__ __launch_bounds__(256, 4) void k_attn(
        const float* __restrict__ z, const float* __restrict__ lzw,
        const float* __restrict__ lzb, const float* __restrict__ Wz,
        const float* __restrict__ QS, const float* __restrict__ KS,
        const float* __restrict__ VS, const float* __restrict__ GS,
        float* __restrict__ OB) {
    __shared__ __align__(16) float s_lds[NH * SROW];   // 32.8 KB scores [h][k], stride 1025
    __shared__ __align__(16) float aux[CZ * NH];       // A (prep), then PV partials (4KB)
    __shared__ float sumA[NH], constB[NH], inv_lds[NH];
    const int tid = threadIdx.x;
    const int q = blockIdx.x;
    const int w = tid >> 6;     // wave 0..3, owns k in [w*256, w*256+256)
    const int l = tid & 63;
    const int j0 = l & 15;      // column sub-index within a z row
    const int row = l >> 4;     // row 0..3 within a 4-row group

    // ---- prep: A[c][h] = lzw[c] * Wz[c][h] into aux ----
    if (tid < CZ) {
        float lw = lzw[tid];
        #pragma unroll
        for (int h = 0; h < NH; ++h) aux[tid * NH + h] = lw * Wz[tid * NH + h];
    }
    __syncthreads();
    if (tid < NH) {
        float sa = 0.f, cb = 0.f;
        for (int c = 0; c < CZ; ++c) {
            sa += aux[c * NH + tid];
            cb += lzb[c] * Wz[c * NH + tid];
        }
        sumA[tid] = sa; constB[tid] = cb;
    }
    // lane-private A columns: c = j0*4 + u*64 + e  (fixed for the whole k-loop)
    float4 al[2][4][2];
    #pragma unroll
    for (int u = 0; u < 2; ++u)
        #pragma unroll
        for (int e = 0; e < 4; ++e) {
            int c = j0 * 4 + u * 64 + e;
            al[u][e][0] = *(const float4*)(aux + c * NH);
            al[u][e][1] = *(const float4*)(aux + c * NH + 4);
        }

    // ---- phase A: s[h][k] = q . k  (coalesced K rows, butterfly over 8 lanes) ----
    {
        const float4 q4 = ((const float4*)(QS + (size_t)q * CIN))[l];
        const float4* K4 = (const float4*)KS;
        const int h = l >> 3;                  // head for cols 4l..4l+3
        float* sdst = s_lds + h * SROW;
        for (int i = 0; i < 256; i += 4) {
            int k0 = (w << 8) + i;
            float4 kv0 = K4[(size_t)(k0 + 0) * 64 + l];
            float4 kv1 = K4[(size_t)(k0 + 1) * 64 + l];
            float4 kv2 = K4[(size_t)(k0 + 2) * 64 + l];
            float4 kv3 = K4[(size_t)(k0 + 3) * 64 + l];
            float d0 = kv0.x*q4.x + kv0.y*q4.y + kv0.z*q4.z + kv0.w*q4.w;
            float d1 = kv1.x*q4.x + kv1.y*q4.y + kv1.z*q4.z + kv1.w*q4.w;
            float d2 = kv2.x*q4.x + kv2.y*q4.y + kv2.z*q4.z + kv2.w*q4.w;
            float d3 = kv3.x*q4.x + kv3.y*q4.y + kv3.z*q4.z + kv3.w*q4.w;
            #pragma unroll
            for (int mm = 1; mm <= 4; mm <<= 1) {
                d0 += __shfl_xor(d0, mm); d1 += __shfl_xor(d1, mm);
                d2 += __shfl_xor(d2, mm); d3 += __shfl_xor(d3, mm);
            }
            if ((l & 7) == 0) {
                sdst[k0] = d0; sdst[k0 + 1] = d1;
                sdst[k0 + 2] = d2; sdst[k0 + 3] = d3;
            }
        }
    }
    __syncthreads();

    // ---- phase B: += pair bias from z (coalesced: 4 rows per 2 loads) ----
    {
        const float4* zb4 = (const float4*)(z + ((size_t)q * R + (size_t)(w << 8)) * CZ);
        const int rb = row * 32 + j0;
        auto process = [&](int g, const float4 v0, const float4 v1) {
            int k = (w << 8) + (g << 2) + row;
            float s1 = v0.x + v0.y + v0.z + v0.w + v1.x + v1.y + v1.z + v1.w;
            float s2 = v0.x*v0.x + v0.y*v0.y + v0.z*v0.z + v0.w*v0.w
                     + v1.x*v1.x + v1.y*v1.y + v1.z*v1.z + v1.w*v1.w;
            float4 da = make_float4(0.f, 0.f, 0.f, 0.f);
            float4 db = make_float4(0.f, 0.f, 0.f, 0.f);
            FMA4(da, v0.x, al[0][0][0]); FMA4(db, v0.x, al[0][0][1]);
            FMA4(da, v0.y, al[0][1][0]); FMA4(db, v0.y, al[0][1][1]);
            FMA4(da, v0.z, al[0][2][0]); FMA4(db, v0.z, al[0][2][1]);
            FMA4(da, v0.w, al[0][3][0]); FMA4(db, v0.w, al[0][3][1]);
            FMA4(da, v1.x, al[1][0][0]); FMA4(db, v1.x, al[1][0][1]);
            FMA4(da, v1.y, al[1][1][0]); FMA4(db, v1.y, al[1][1][1]);
            FMA4(da, v1.z, al[1][2][0]); FMA4(db, v1.z, al[1][2][1]);
            FMA4(da, v1.w, al[1][3][0]); FMA4(db, v1.w, al[1][3][1]);
            #pragma unroll
            for (int mm = 1; mm <= 8; mm <<= 1) {
                s1 += __shfl_xor(s1, mm);     s2 += __shfl_xor(s2, mm);
                da.x += __shfl_xor(da.x, mm); da.y += __shfl_xor(da.y, mm);
                da.z += __shfl_xor(da.z, mm); da.w += __shfl_xor(da.w, mm);
                db.x += __shfl_xor(db.x, mm); db.y += __shfl_xor(db.y, mm);
                db.z += __shfl_xor(db.z, mm); db.w += __shfl_xor(db.w, mm);
            }
            float mu = s1 * (1.0f / CZ);
            float var = s2 * (1.0f / CZ) - mu * mu;
            float rstd = rsqrtf(var + EPS);
            if (j0 < 8) {
                float dh = (j0 & 4) ? ((j0 & 2) ? ((j0 & 1) ? db.w : db.z)
                                                : ((j0 & 1) ? db.y : db.x))
                                    : ((j0 & 2) ? ((j0 & 1) ? da.w : da.z)
                                                : ((j0 & 1) ? da.y : da.x));
                float bias = rstd * (dh - mu * sumA[j0]) + constB[j0];
                s_lds[j0 * SROW + k] += bias;
            }
        };
        float4 A0 = zb4[rb], A1 = zb4[rb + 16];
        for (int g = 0; g < 64; ++g) {
            int gn = (g + 1) & 63;
            float4 N0 = zb4[rb + gn * 128];
            float4 N1 = zb4[rb + gn * 128 + 16];
            process(g, A0, A1);
            A0 = N0; A1 = N1;
        }
    }
    __syncthreads();

    // ---- phase C: softmax per head (32 lanes per head) ----
    {
        int r = tid >> 5, j = tid & 31;
        float* srow = s_lds + r * SROW;
        float mx = -1e30f;
        #pragma unroll 4
        for (int i = 0; i < 32; ++i) mx = fmaxf(mx, srow[j + i * 32]);
        #pragma unroll
        for (int mm = 1; mm < 32; mm <<= 1) mx = fmaxf(mx, __shfl_xor(mx, mm));
        float sum = 0.f;
        #pragma unroll 4
        for (int i = 0; i < 32; ++i) {
            float e = __expf(srow[j + i * 32] - mx);
            srow[j + i * 32] = e;
            sum += e;
        }
        #pragma unroll
        for (int mm = 1; mm < 32; mm <<= 1) sum += __shfl_xor(sum, mm);
        if (j == 0) inv_lds[r] = 1.f / sum;
    }
    __syncthreads();

    // ---- phase D: o = P.V (coalesced V rows, P broadcast from LDS) ----
    {
        const float4* V4 = (const float4*)VS;
        const int h = l >> 3;
        const float* prow = s_lds + h * SROW;
        float4 o = make_float4(0.f, 0.f, 0.f, 0.f);
        for (int i = 0; i < 256; i += 4) {
            int k0 = (w << 8) + i;
            float4 v0 = V4[(size_t)(k0 + 0) * 64 + l];
            float4 v1 = V4[(size_t)(k0 + 1) * 64 + l];
            float4 v2 = V4[(size_t)(k0 + 2) * 64 + l];
            float4 v3 = V4[(size_t)(k0 + 3) * 64 + l];
            float p0 = prow[k0], p1 = prow[k0 + 1], p2 = prow[k0 + 2], p3 = prow[k0 + 3];
            FMA4(o, p0, v0); FMA4(o, p1, v1); FMA4(o, p2, v2); FMA4(o, p3, v3);
        }
        ((float4*)aux)[w * 64 + l] = o;   // aux[w*256 + 4l..4l+3]
    }
    __syncthreads();
    {
        float s = aux[tid] + aux[256 + tid] + aux[512 + tid] + aux[768 + tid];
        float o = s * inv_lds[tid >> 5] * GS[(size_t)q * CIN + tid];
        OB[(size_t)q * CIN + tid] = o;
    }
}

// ---------------- K4: out = OB @ Wo + bo ----------------
__global__ __launch_bounds__(256) void k_out(const float* __restrict__ OB,
        const float* __restrict__ Wo, const float* __restrict__ bo,
        float* __restrict__ out) {
    __shared__ __align__(16) float mnt[CIN * 4];
    int tid = threadIdx.x;
    int qb = blockIdx.x * 4;
    #pragma unroll
    for (int r = 0; r < 4; ++r)
        mnt[tid * 4 + r] = OB[(qb + r) * CIN + tid];
    __syncthreads();
    const float4* mt4 = (const float4*)mnt;
    float acc[4] = {0.f, 0.f, 0.f, 0.f};
    #pragma unroll 4
    for (int g = 0; g < 32; ++g) {
        #pragma unroll
        for (int u = 0; u < 8; ++u) {
            float wv = Wo[(g * 8 + u) * 256 + tid];
            float4 mv = mt4[g * 8 + u];
            acc[0] += mv.x * wv; acc[1] += mv.y * wv;
            acc[2] += mv.z * wv; acc[3] += mv.w * wv;
        }
    }
    float bv = bo[tid];
    #pragma unroll
    for (int r = 0; r < 4; ++r)
        out[(qb + r) * 256 + tid] = acc[r] + bv;
}

extern "C" void kernel_launch(void* const* d_in, const int* in_sizes, int n_in,
                              void* d_out, int out_size, void* d_ws, size_t ws_size,
                              hipStream_t stream) {
    (void)in_sizes; (void)n_in; (void)out_size; (void)ws_size;
    const float* m   = (const float*)d_in[0];
    const float* z   = (const float*)d_in[1];
    const float* lmw = (const float*)d_in[2];
    const float* lmb = (const float*)d_in[3];
    const float* lzw = (const float*)d_in[4];
    const float* lzb = (const float*)d_in[5];
    const float* Wz  = (const float*)d_in[6];
    const float* Wq  = (const float*)d_in[7];
    const float* Wk  = (const float*)d_in[8];
    const float* Wv  = (const float*)d_in[9];
    const float* Wg  = (const float*)d_in[10];
    const float* Wo  = (const float*)d_in[12];
    const float* bo  = (const float*)d_in[13];
    float* ws = (float*)d_ws;
    float* MN = ws;                 // 1024*256
    float* QS = ws + 262144;
    float* KS = ws + 524288;
    float* VS = ws + 786432;
    float* GS = ws + 1048576;
    float* OB = ws + 1310720;
    float* out = (float*)d_out;

    hipLaunchKernelGGL(k_ln_m, dim3(R), dim3(256), 0, stream, m, lmw, lmb, MN);
    hipLaunchKernelGGL(k_qkvg, dim3(1024), dim3(256), 0, stream,
                       MN, Wq, Wk, Wv, Wg, QS, KS, VS, GS);
    hipLaunchKernelGGL(k_attn, dim3(R), dim3(256), 0, stream,
                       z, lzw, lzb, Wz, QS, KS, VS, GS, OB);
    hipLaunchKernelGGL(k_out, dim3(256), dim3(256), 0, stream, OB, Wo, bo, out);
}